// Round 11
// baseline (546.224 us; speedup 1.0000x reference)
//
#include <hip/hip_runtime.h>

#define NN 50000
#define NE 500000
#define DD 128
#define NL 4
#define NG 64
#define FIXED_DIM 10000
#define BN_EPS 1e-5f
#define NB 196   // ceil(NN/256)

typedef unsigned short u16;
typedef unsigned int u32;
typedef __attribute__((ext_vector_type(8))) short bf16x8;
typedef __attribute__((ext_vector_type(4))) float f32x4;

__device__ __forceinline__ float bf2f(u16 u) {
    return __uint_as_float(((u32)u) << 16);
}
__device__ __forceinline__ u16 f2bf(float f) {
    u32 u = __float_as_uint(f);
    return (u16)((u + 0x7FFFu + ((u >> 16) & 1u)) >> 16);
}
// adaptive float-INPUT load (isbf: bf16 vs fp32)
__device__ __forceinline__ float ldf(const void* p, size_t i, int isbf) {
    return isbf ? bf2f(((const u16*)p)[i]) : ((const float*)p)[i];
}

// fused preamble: block 0 = dtype probe (writes flag); block 1 = goff binary
// search; blocks [2, 2+zb) = zero of [stats .. sem]; blocks [2+zb, 2+zb+12) =
// param convert (6 tensors -> fp32); blocks [2+zb+12, ...) = weight swizzle.
// cvt/swz blocks recompute the dtype flag locally (256B L2-hit read + short
// shared reduce) so they have no dependency on block 0 — this merges the old
// k_cvtswz kernel into k_pre (one less launch, earlier start).
// Wsw[m*16384 + ((nt*4+ks)*64 + lane)*8 + j]
//   = W_m[ks*32 + (lane>>4)*8 + j][nt*16 + (lane&15)]   (bf16)
__global__ void k_pre(const void* __restrict__ vb, int* __restrict__ flag,
                      const int* __restrict__ batch, int* __restrict__ goff,
                      float* __restrict__ zbase, int zwords,
                      const void* b1, const void* b2, const void* g1,
                      const void* be1, const void* g2, const void* be2,
                      const void* __restrict__ w1, const void* __restrict__ w2,
                      float* __restrict__ pc, u16* __restrict__ Wsw) {
    __shared__ int shm[256];
    int b = blockIdx.x, t = threadIdx.x;
    int zb = (zwords + 255) >> 8;
    if (b == 0) {
        float v = (t < 128) ? bf2f(((const u16*)vb)[t]) : 0.f;
        shm[t] = (t < 128) ? ((fabsf(v) < 1000.f) ? 1 : 0) : 1;
        __syncthreads();
        for (int off = 128; off; off >>= 1) {
            if (t < off) shm[t] &= shm[t + off];
            __syncthreads();
        }
        if (t == 0) *flag = shm[0];
    } else if (b == 1) {
        if (t <= NG) {
            int lo = 0, hi = NN;
            while (lo < hi) {
                int mid = (lo + hi) >> 1;
                if (batch[mid] < t) lo = mid + 1; else hi = mid;
            }
            goff[t] = lo;
        }
    } else if (b < 2 + zb) {
        int i = (b - 2) * 256 + t;
        if (i < zwords) zbase[i] = 0.f;
    } else {
        // local dtype probe (no dependency on block 0)
        float v = (t < 128) ? bf2f(((const u16*)vb)[t]) : 0.f;
        shm[t] = (t < 128) ? ((fabsf(v) < 1000.f) ? 1 : 0) : 1;
        __syncthreads();
        for (int off = 128; off; off >>= 1) {
            if (t < off) shm[t] &= shm[t + off];
            __syncthreads();
        }
        int isbf = shm[0];
        int bb = b - 2 - zb;
        if (bb < 12) {
            int i = bb * 256 + t;            // < 3072 exactly
            int p = i >> 9, j = i & 511;
            const void* s = (p == 0) ? b1 : (p == 1) ? b2 : (p == 2) ? g1
                          : (p == 3) ? be1 : (p == 4) ? g2 : be2;
            pc[i] = ldf(s, j, isbf);
        } else {
            int i = (bb - 12) * 256 + t;     // < 131072 exactly
            int m    = i >> 14;
            int idx  = i & 16383;
            int nt   = idx >> 11;
            int ks   = (idx >> 9) & 3;
            int lane = (idx >> 3) & 63;
            int j    = idx & 7;
            int row = ks * 32 + (lane >> 4) * 8 + j;
            int col = nt * 16 + (lane & 15);
            const void* src = (m < 4) ? w1 : w2;
            size_t off = (size_t)(m & 3) * DD * DD + (size_t)row * DD + col;
            Wsw[i] = f2bf(ldf(src, off, isbf));
        }
    }
}

__global__ void k_deg(const int* __restrict__ dst, int* __restrict__ deg) {
    int i = blockIdx.x * 256 + threadIdx.x;
    if (i < NE) atomicAdd(&deg[dst[i]], 1);
}

// scan stage 1 + (last-block) stage 2: per-block sums -> exclusive scan of bsum.
// Device-scope atomics for cross-XCD visibility within the kernel.
__global__ void k_scan12(const int* __restrict__ deg, int* __restrict__ bsum,
                         int* __restrict__ sem) {
    __shared__ int S[256];
    __shared__ int lastB;
    int b = blockIdx.x, t = threadIdx.x;
    int i = b * 256 + t;
    S[t] = (i < NN) ? deg[i] : 0;
    __syncthreads();
    for (int off = 128; off; off >>= 1) {
        if (t < off) S[t] += S[t + off];
        __syncthreads();
    }
    if (t == 0) {
        atomicExch(&bsum[b], S[0]);
        __threadfence();
        lastB = (atomicAdd(&sem[0], 1) == gridDim.x - 1);
    }
    __syncthreads();
    if (!lastB) return;
    __threadfence();
    int v = (t < NB) ? atomicAdd(&bsum[t], 0) : 0;
    S[t] = v;
    __syncthreads();
    for (int off = 1; off < 256; off <<= 1) {
        int x = (t >= off) ? S[t - off] : 0;
        __syncthreads();
        S[t] += x;
        __syncthreads();
    }
    if (t < NB) bsum[t] = S[t] - v;                 // exclusive
}

// merged: blocks 0..NB-1 finish the rowptr scan; blocks NB.. compute
// h0 = vw[feat] + vb + deg_emb[min(deg,1000)] -> B (bf16).
// Init phase vectorized: 8 cols/thread, uint4 loads/stores.
__global__ void k_scan3init(const int* __restrict__ deg, const int* __restrict__ bsum,
                            int* __restrict__ rowptr,
                            const int* __restrict__ feat, const void* __restrict__ vw,
                            const void* __restrict__ vb, const void* __restrict__ demb,
                            u16* __restrict__ B, const int* __restrict__ flag) {
    __shared__ int S[256];
    int b = blockIdx.x, t = threadIdx.x;
    if (b < NB) {
        int i = b * 256 + t;
        int v = (i < NN) ? deg[i] : 0;
        S[t] = v;
        __syncthreads();
        for (int off = 1; off < 256; off <<= 1) {
            int x = (t >= off) ? S[t - off] : 0;
            __syncthreads();
            S[t] += x;
            __syncthreads();
        }
        if (i < NN) rowptr[i] = bsum[b] + S[t] - v;
        if (i == NN - 1) rowptr[NN] = bsum[b] + S[t];   // == NE
    } else {
        int idx = (b - NB) * 256 + t;            // < 800000 exactly
        if (idx >= NN * DD / 8) return;
        int n  = idx >> 4;                       // 16 threads per node
        int c8 = (idx & 15) * 8;
        int isbf = *flag;
        int f  = feat[n] % FIXED_DIM;
        int dg = min(deg[n], 1000);
        float x[8];
        if (isbf) {
            uint4 a4 = *(const uint4*)((const u16*)vw + (size_t)f * DD + c8);
            uint4 b4 = *(const uint4*)((const u16*)vb + c8);
            uint4 d4 = *(const uint4*)((const u16*)demb + (size_t)dg * DD + c8);
            u32 aw[4] = {a4.x, a4.y, a4.z, a4.w};
            u32 bw[4] = {b4.x, b4.y, b4.z, b4.w};
            u32 dw[4] = {d4.x, d4.y, d4.z, d4.w};
            #pragma unroll
            for (int e = 0; e < 8; e++) {
                int wi = e >> 1, sh = (e & 1) * 16;
                x[e] = bf2f((u16)(aw[wi] >> sh)) + bf2f((u16)(bw[wi] >> sh))
                     + bf2f((u16)(dw[wi] >> sh));
            }
        } else {
            const float* vwp = (const float*)vw + (size_t)f * DD + c8;
            const float* vbp = (const float*)vb + c8;
            const float* dep = (const float*)demb + (size_t)dg * DD + c8;
            #pragma unroll
            for (int e = 0; e < 8; e++) x[e] = vwp[e] + vbp[e] + dep[e];
        }
        u32 o0 = ((u32)f2bf(x[1]) << 16) | (u32)f2bf(x[0]);
        u32 o1 = ((u32)f2bf(x[3]) << 16) | (u32)f2bf(x[2]);
        u32 o2 = ((u32)f2bf(x[5]) << 16) | (u32)f2bf(x[4]);
        u32 o3 = ((u32)f2bf(x[7]) << 16) | (u32)f2bf(x[6]);
        *(uint4*)&B[(size_t)idx * 8] = make_uint4(o0, o1, o2, o3);
    }
}

__global__ void k_fill(const int* __restrict__ src, const int* __restrict__ dst,
                       const int* __restrict__ rowptr, int* __restrict__ cursor,
                       int* __restrict__ colidx) {
    int e = blockIdx.x * 256 + threadIdx.x;
    if (e >= NE) return;
    int d = dst[e];
    int p = atomicAdd(&cursor[d], 1);
    colidx[rowptr[d] + p] = src[e];
}

// GIN aggregation with fused h-recompute, bf16 out (proven structure:
// 1 row/wave, 2 cols/lane, occupancy 8 -> max TLP for the latency-bound gather).
//   f(x) = AFF ? relu(a[c]*x + b[c]) : x   (a,b from prev layer's BN2 stats)
//   Agg[n] = f(B[n]) + sum_{j in row n} f(B[colidx[j]])
template <bool AFF>
__global__ __launch_bounds__(256, 8) void k_aggr(
        const u16* __restrict__ B, const int* __restrict__ rowptr,
        const int* __restrict__ colidx,
        const float* __restrict__ gIn, const float* __restrict__ bIn,
        const float* __restrict__ sIn, const float* __restrict__ qIn,
        u16* __restrict__ Agg) {
    int n = blockIdx.x * 4 + (threadIdx.x >> 6);
    if (n >= NN) return;
    int c = (threadIdx.x & 63) * 2;
    float a0 = 1.f, b0 = 0.f, a1 = 1.f, b1 = 0.f;
    if (AFF) {
        float inv = 1.0f / (float)NN;
        float mu0 = sIn[c] * inv, mu1 = sIn[c + 1] * inv;
        float v0 = fmaxf(qIn[c] * inv - mu0 * mu0, 0.f);
        float v1 = fmaxf(qIn[c + 1] * inv - mu1 * mu1, 0.f);
        a0 = gIn[c] * rsqrtf(v0 + BN_EPS);
        a1 = gIn[c + 1] * rsqrtf(v1 + BN_EPS);
        b0 = bIn[c] - a0 * mu0;
        b1 = bIn[c + 1] - a1 * mu1;
    }
    u32 w = *(const u32*)&B[(size_t)n * DD + c];
    float x0 = bf2f((u16)(w & 0xFFFF)), x1 = bf2f((u16)(w >> 16));
    float s0 = AFF ? fmaxf(fmaf(a0, x0, b0), 0.f) : x0;
    float s1 = AFF ? fmaxf(fmaf(a1, x1, b1), 0.f) : x1;
    int lo = rowptr[n], hi = rowptr[n + 1];
    int j = lo;
    for (; j + 4 <= hi; j += 4) {
        int m0 = colidx[j], m1 = colidx[j + 1];
        int m2 = colidx[j + 2], m3 = colidx[j + 3];
        u32 w0 = *(const u32*)&B[(size_t)m0 * DD + c];
        u32 w1v = *(const u32*)&B[(size_t)m1 * DD + c];
        u32 w2v = *(const u32*)&B[(size_t)m2 * DD + c];
        u32 w3v = *(const u32*)&B[(size_t)m3 * DD + c];
        float y;
        y = bf2f((u16)(w0 & 0xFFFF)); s0 += AFF ? fmaxf(fmaf(a0, y, b0), 0.f) : y;
        y = bf2f((u16)(w0 >> 16));    s1 += AFF ? fmaxf(fmaf(a1, y, b1), 0.f) : y;
        y = bf2f((u16)(w1v & 0xFFFF)); s0 += AFF ? fmaxf(fmaf(a0, y, b0), 0.f) : y;
        y = bf2f((u16)(w1v >> 16));    s1 += AFF ? fmaxf(fmaf(a1, y, b1), 0.f) : y;
        y = bf2f((u16)(w2v & 0xFFFF)); s0 += AFF ? fmaxf(fmaf(a0, y, b0), 0.f) : y;
        y = bf2f((u16)(w2v >> 16));    s1 += AFF ? fmaxf(fmaf(a1, y, b1), 0.f) : y;
        y = bf2f((u16)(w3v & 0xFFFF)); s0 += AFF ? fmaxf(fmaf(a0, y, b0), 0.f) : y;
        y = bf2f((u16)(w3v >> 16));    s1 += AFF ? fmaxf(fmaf(a1, y, b1), 0.f) : y;
    }
    for (; j < hi; j++) {
        int m = colidx[j];
        w = *(const u32*)&B[(size_t)m * DD + c];
        x0 = bf2f((u16)(w & 0xFFFF)); x1 = bf2f((u16)(w >> 16));
        s0 += AFF ? fmaxf(fmaf(a0, x0, b0), 0.f) : x0;
        s1 += AFF ? fmaxf(fmaf(a1, x1, b1), 0.f) : x1;
    }
    *(u32*)&Agg[(size_t)n * DD + c] = ((u32)f2bf(s1) << 16) | (u32)f2bf(s0);
}

// ---- MFMA GEMM, 128x128 per block, FULLY DIRECT-GLOBAL (A and W) ----
// W fragments are loaded straight from global Wsw inside the ks-loop.
// Rationale: the access ((nt*4+ks)*64+ln)*8 is ln-consecutive (1KB coalesced
// per instruction) and one layer's Wsw is 32KB = L1-sized, so all waves
// after the first hit L1. This removes the LDS staging loop (2048 writes)
// + a barrier from a latency-dominated single-shot kernel (same mechanism
// as the round-7 A-tile removal, which measured -46us). LDS now just
// Red+aff (5KB). 8 W-frags live at a time keeps VGPR ~150 within the
// (256,3) cap. Values and op order identical to the LDS version.
template <bool IN16, bool OUT16, bool AFF>
__global__ __launch_bounds__(256, 3) void k_gemm(
        const void* In, const u16* __restrict__ Wsw,
        const float* __restrict__ bias,
        const float* __restrict__ gIn, const float* __restrict__ bIn,
        const float* __restrict__ sIn, const float* __restrict__ qIn,
        void* Out, float* __restrict__ ssum, float* __restrict__ ssq,
        int nRows) {
    __shared__ float RedS[512];
    __shared__ float RedQ[512];
    __shared__ float affS[256];
    const int t = threadIdx.x;
    const int row0 = blockIdx.x * 128;

    if (AFF) {
        if (t < 128) {
            float inv = 1.0f / (float)NN;
            float mu = sIn[t] * inv;
            float var = fmaxf(qIn[t] * inv - mu * mu, 0.f);
            float a = gIn[t] * rsqrtf(var + BN_EPS);
            affS[t] = a;
            affS[128 + t] = bIn[t] - a * mu;
        }
        __syncthreads();
    }

    const int w    = t >> 6;
    const int ln   = t & 63;
    const int quad = ln >> 4;
    const int lq   = ln & 15;
    const int r0g  = row0 + w * 32 + lq;     // M-tile 0 row
    const int r1g  = r0g + 16;               // M-tile 1 row

    // A fragments directly from global (zeros for OOB rows)
    bf16x8 af0[4], af1[4];
    #pragma unroll
    for (int ks = 0; ks < 4; ks++) {
        const int cb = quad * 8 + ks * 32;
        if (IN16) {
            const u16* p = (const u16*)In;
            af0[ks] = (r0g < nRows) ? *(const bf16x8*)&p[(size_t)r0g * DD + cb]
                                    : (bf16x8){0,0,0,0,0,0,0,0};
            af1[ks] = (r1g < nRows) ? *(const bf16x8*)&p[(size_t)r1g * DD + cb]
                                    : (bf16x8){0,0,0,0,0,0,0,0};
        } else {
            const float* p = (const float*)In;
            bf16x8 v0 = {0,0,0,0,0,0,0,0}, v1 = {0,0,0,0,0,0,0,0};
            if (r0g < nRows) {
                const float* rp = p + (size_t)r0g * DD + cb;
                float4 lo = *(const float4*)rp;
                float4 hi = *(const float4*)(rp + 4);
                float xs[8] = {lo.x, lo.y, lo.z, lo.w, hi.x, hi.y, hi.z, hi.w};
                #pragma unroll
                for (int e = 0; e < 8; e++) {
                    float x = xs[e];
                    if (AFF) x = fmaxf(fmaf(affS[cb + e], x, affS[128 + cb + e]), 0.f);
                    v0[e] = (short)f2bf(x);
                }
            }
            if (r1g < nRows) {
                const float* rp = p + (size_t)r1g * DD + cb;
                float4 lo = *(const float4*)rp;
                float4 hi = *(const float4*)(rp + 4);
                float xs[8] = {lo.x, lo.y, lo.z, lo.w, hi.x, hi.y, hi.z, hi.w};
                #pragma unroll
                for (int e = 0; e < 8; e++) {
                    float x = xs[e];
                    if (AFF) x = fmaxf(fmaf(affS[cb + e], x, affS[128 + cb + e]), 0.f);
                    v1[e] = (short)f2bf(x);
                }
            }
            af0[ks] = v0;
            af1[ks] = v1;
        }
    }

    f32x4 acc0[8], acc1[8];
    #pragma unroll
    for (int nt = 0; nt < 8; nt++) {
        acc0[nt] = (f32x4){0.f, 0.f, 0.f, 0.f};
        acc1[nt] = (f32x4){0.f, 0.f, 0.f, 0.f};
    }
    #pragma unroll
    for (int ks = 0; ks < 4; ks++) {
        bf16x8 wf[8];
        #pragma unroll
        for (int nt = 0; nt < 8; nt++)
            wf[nt] = *(const bf16x8*)&Wsw[((size_t)(nt * 4 + ks) * 64 + ln) * 8];
        #pragma unroll
        for (int nt = 0; nt < 8; nt++) {
            acc0[nt] = __builtin_amdgcn_mfma_f32_16x16x32_bf16(af0[ks], wf[nt], acc0[nt], 0, 0, 0);
            acc1[nt] = __builtin_amdgcn_mfma_f32_16x16x32_bf16(af1[ks], wf[nt], acc1[nt], 0, 0, 0);
        }
    }

    // epilogue: D[row=quad*4+r][col=nt*16+lq] for both M-tiles
    const int rb0 = row0 + w * 32 + quad * 4;
    const int rb1 = rb0 + 16;
    #pragma unroll
    for (int nt = 0; nt < 8; nt++) {
        int col = nt * 16 + lq;
        float bv = bias[col];
        float s = 0.f, q = 0.f;
        #pragma unroll
        for (int r = 0; r < 4; r++) {
            int gr = rb0 + r;
            if (gr < nRows) {
                float val = acc0[nt][r] + bv;
                size_t o = (size_t)gr * DD + col;
                if (OUT16) ((u16*)Out)[o] = f2bf(val);
                else       ((float*)Out)[o] = val;
                s += val; q += val * val;
            }
        }
        #pragma unroll
        for (int r = 0; r < 4; r++) {
            int gr = rb1 + r;
            if (gr < nRows) {
                float val = acc1[nt][r] + bv;
                size_t o = (size_t)gr * DD + col;
                if (OUT16) ((u16*)Out)[o] = f2bf(val);
                else       ((float*)Out)[o] = val;
                s += val; q += val * val;
            }
        }
        s += __shfl_xor(s, 16); q += __shfl_xor(q, 16);
        s += __shfl_xor(s, 32); q += __shfl_xor(q, 32);
        if (quad == 0) { RedS[w * 128 + col] = s; RedQ[w * 128 + col] = q; }
    }
    __syncthreads();
    if (t < 128) {
        float s = RedS[t] + RedS[128 + t] + RedS[256 + t] + RedS[384 + t];
        float q = RedQ[t] + RedQ[128 + t] + RedQ[256 + t] + RedQ[384 + t];
        atomicAdd(&ssum[t], s);
        atomicAdd(&ssq[t], q);
    }
}

// final h = relu(a*z2+b) -> A (fp32) + pool partials; last block divides.
// (round-7 form, best measured; d_out write path caps this kernel ~45us)
__global__ __launch_bounds__(256, 4) void k_upool(
        const u16* __restrict__ Bz,
        const float* __restrict__ gIn, const float* __restrict__ bIn,
        const float* __restrict__ sIn, const float* __restrict__ qIn,
        const int* __restrict__ batch, float* __restrict__ A,
        float* __restrict__ gsum, const int* __restrict__ goff,
        float* __restrict__ outw, int* __restrict__ sem) {
    const int t = threadIdx.x;
    const int c = (t & 63) * 2;        // 2 cols per lane
    const int qv = t >> 6;             // rows qv + 4i (wave-uniform row)
    const int r0 = blockIdx.x * 64;
    const int g_lo = batch[r0];
    const int g_hi = batch[min(r0 + 63, NN - 1)];
    float inv = 1.0f / (float)NN;
    float mu0 = sIn[c] * inv, mu1 = sIn[c + 1] * inv;
    float v0 = fmaxf(qIn[c] * inv - mu0 * mu0, 0.f);
    float v1 = fmaxf(qIn[c + 1] * inv - mu1 * mu1, 0.f);
    float a0 = gIn[c] * rsqrtf(v0 + BN_EPS);
    float a1 = gIn[c + 1] * rsqrtf(v1 + BN_EPS);
    float b0 = bIn[c] - a0 * mu0;
    float b1 = bIn[c + 1] - a1 * mu1;
    float lo0 = 0.f, lo1 = 0.f, hi0 = 0.f, hi1 = 0.f;
    #pragma unroll
    for (int i = 0; i < 16; i++) {
        int r = r0 + qv + 4 * i;
        if (r >= NN) break;
        u32 wd = *(const u32*)&Bz[(size_t)r * DD + c];
        float x0 = fmaxf(fmaf(a0, bf2f((u16)(wd & 0xFFFF)), b0), 0.f);
        float x1 = fmaxf(fmaf(a1, bf2f((u16)(wd >> 16)), b1), 0.f);
        *(float2*)&A[(size_t)r * DD + c] = make_float2(x0, x1);
        if (batch[r] == g_lo) { lo0 += x0; lo1 += x1; }
        else                  { hi0 += x0; hi1 += x1; }
    }
    __shared__ float2 PL[4][64];
    __shared__ float2 PH[4][64];
    PL[qv][t & 63] = make_float2(lo0, lo1);
    PH[qv][t & 63] = make_float2(hi0, hi1);
    __syncthreads();
    if (t < 64) {
        float2 p0 = PL[0][t], p1 = PL[1][t], p2 = PL[2][t], p3 = PL[3][t];
        atomicAdd(&gsum[(size_t)g_lo * DD + 2 * t],     p0.x + p1.x + p2.x + p3.x);
        atomicAdd(&gsum[(size_t)g_lo * DD + 2 * t + 1], p0.y + p1.y + p2.y + p3.y);
    } else if (t < 128 && g_hi != g_lo) {
        int u = t - 64;
        float2 p0 = PH[0][u], p1 = PH[1][u], p2 = PH[2][u], p3 = PH[3][u];
        atomicAdd(&gsum[(size_t)g_hi * DD + 2 * u],     p0.x + p1.x + p2.x + p3.x);
        atomicAdd(&gsum[(size_t)g_hi * DD + 2 * u + 1], p0.y + p1.y + p2.y + p3.y);
    }

    __shared__ int lastF;
    if (t == 0) {
        __threadfence();
        lastF = (atomicAdd(&sem[1], 1) == gridDim.x - 1);
    }
    __syncthreads();
    if (!lastF) return;
    __threadfence();
    for (int i = t; i < NG * DD; i += 256) {
        int g = i >> 7;
        float cnt = fmaxf((float)(goff[g + 1] - goff[g]), 1.0f);
        outw[i] = atomicAdd(&gsum[i], 0.0f) / cnt;
    }
}

extern "C" void kernel_launch(void* const* d_in, const int* in_sizes, int n_in,
                              void* d_out, int out_size, void* d_ws, size_t ws_size,
                              hipStream_t stream) {
    const int* feat  = (const int*)d_in[0];
    const int* ei    = (const int*)d_in[1];
    const int* batch = (const int*)d_in[2];
    const void* vw   = d_in[3];
    const void* vb   = d_in[4];
    const void* demb = d_in[5];
    const void* w1   = d_in[6];
    const void* b1   = d_in[7];
    const void* g1   = d_in[8];
    const void* be1  = d_in[9];
    const void* w2   = d_in[10];
    const void* b2   = d_in[11];
    const void* g2   = d_in[12];
    const void* be2  = d_in[13];

    const int* src = ei;
    const int* dst = ei + NE;
    const size_t ND = (size_t)NN * DD;

    // ---- workspace layout ----
    float* pc     = (float*)d_ws;            // 3072: b1,b2,g1,be1,g2,be2
    int*   flag   = (int*)(pc + 3072);       // 64
    float* stats  = (float*)(flag + 64);     // 2048 [zero from here...]
    float* gsum   = stats + 2048;            // 8192
    int*   deg    = (int*)(gsum + 8192);     // NN
    int*   cursor = deg + NN;                // NN
    int*   sem    = cursor + NN;             // 64  [...to here]
    int*   bsum   = sem + 64;                // 256
    int*   goff   = bsum + 256;              // 128 (65 used)
    int*   rowptr = goff + 128;              // NN+64
    int*   colidx = rowptr + NN + 64;        // NE
    u16*   Wsw    = (u16*)(colidx + NE);     // 8*16384 u16
    u16*   B      = Wsw + 8 * 16384;         // ND bf16
    u16*   Agg16  = B + ND;                  // ND bf16
    float* Z      = (float*)(Agg16 + ND);    // ND fp32: z1 scratch (in ws)

    float* b1c  = pc;
    float* b2c  = pc + 512;
    float* g1c  = pc + 1024;
    float* be1c = pc + 1536;
    float* g2c  = pc + 2048;
    float* be2c = pc + 2560;
    float* sum1 = stats;          // [NL][128]
    float* sq1  = stats + 512;
    float* sum2 = stats + 1024;
    float* sq2  = stats + 1536;

    float* outw = (float*)d_out;             // [0, NG*DD): graph_feature
    float* A    = outw + (size_t)NG * DD;    // final h (fp32) — d_out only

    const int zwords = 2048 + 8192 + NN + NN + 64;  // stats, gsum, deg, cursor, sem
    const int zb = (zwords + 255) / 256;            // 431
    const int initBlocks = (int)(ND / 8 / 256);     // 3125 exact
    const int gemmBlocks = (NN + 127) / 128;        // 391
    const int aggrBlocks = (NN + 3) / 4;            // 12500

    k_pre<<<2 + zb + 12 + 512, 256, 0, stream>>>(vb, flag, batch, goff,
                                                 stats, zwords,
                                                 b1, b2, g1, be1, g2, be2,
                                                 w1, w2, pc, Wsw);
    k_deg<<<(NE + 255) / 256, 256, 0, stream>>>(dst, deg);
    k_scan12<<<NB, 256, 0, stream>>>(deg, bsum, sem);
    k_scan3init<<<NB + initBlocks, 256, 0, stream>>>(deg, bsum, rowptr,
                                                     feat, vw, vb, demb, B, flag);
    k_fill<<<(NE + 255) / 256, 256, 0, stream>>>(src, dst, rowptr, cursor, colidx);

    for (int l = 0; l < NL; l++) {
        const u16* W1l = Wsw + (size_t)l * 16384;
        const u16* W2l = Wsw + (size_t)(4 + l) * 16384;
        if (l == 0) {
            k_aggr<false><<<aggrBlocks, 256, 0, stream>>>(
                B, rowptr, colidx, nullptr, nullptr, nullptr, nullptr, Agg16);
        } else {
            k_aggr<true><<<aggrBlocks, 256, 0, stream>>>(
                B, rowptr, colidx, g2c + (l - 1) * 128, be2c + (l - 1) * 128,
                sum2 + (l - 1) * 128, sq2 + (l - 1) * 128, Agg16);
        }
        // GEMM1: Agg16 (bf16) -> Z (fp32 z1, in workspace)
        k_gemm<true, false, false><<<gemmBlocks, 256, 0, stream>>>(
            Agg16, W1l, b1c + l * 128, nullptr, nullptr, nullptr, nullptr,
            Z, sum1 + l * 128, sq1 + l * 128, NN);
        // GEMM2: Z (fp32 z1) -> B (bf16 z2), affine from BN1 stats
        k_gemm<false, true, true><<<gemmBlocks, 256, 0, stream>>>(
            Z, W2l, b2c + l * 128, g1c + l * 128, be1c + l * 128,
            sum1 + l * 128, sq1 + l * 128,
            B, sum2 + l * 128, sq2 + l * 128, NN);
    }
    k_upool<<<(NN + 63) / 64, 256, 0, stream>>>(
        B, g2c + 3 * 128, be2c + 3 * 128, sum2 + 3 * 128, sq2 + 3 * 128,
        batch, A, gsum, goff, outw, sem);
}

// Round 12
// 520.943 us; speedup vs baseline: 1.0485x; 1.0485x over previous
//
#include <hip/hip_runtime.h>

#define NN 50000
#define NE 500000
#define DD 128
#define NL 4
#define NG 64
#define FIXED_DIM 10000
#define BN_EPS 1e-5f
#define NB 196   // ceil(NN/256)

typedef unsigned short u16;
typedef unsigned int u32;
typedef __attribute__((ext_vector_type(8))) short bf16x8;
typedef __attribute__((ext_vector_type(4))) float f32x4;

__device__ __forceinline__ float bf2f(u16 u) {
    return __uint_as_float(((u32)u) << 16);
}
__device__ __forceinline__ u16 f2bf(float f) {
    u32 u = __float_as_uint(f);
    return (u16)((u + 0x7FFFu + ((u >> 16) & 1u)) >> 16);
}
// adaptive float-INPUT load (isbf: bf16 vs fp32)
__device__ __forceinline__ float ldf(const void* p, size_t i, int isbf) {
    return isbf ? bf2f(((const u16*)p)[i]) : ((const float*)p)[i];
}

// fused preamble: block 0 = dtype probe (writes flag); block 1 = goff binary
// search; blocks [2, 2+zb) = zero of [stats .. sem]; blocks [2+zb, 2+zb+12) =
// param convert (6 tensors -> fp32); blocks [2+zb+12, ...) = weight swizzle.
// cvt/swz blocks recompute the dtype flag locally so they have no dependency
// on block 0 (merges old k_cvtswz into k_pre; kept from round 10 — startup
// block-range split, mechanism independent of the GEMM W-load regression).
// Wsw[m*16384 + ((nt*4+ks)*64 + lane)*8 + j]
//   = W_m[ks*32 + (lane>>4)*8 + j][nt*16 + (lane&15)]   (bf16)
__global__ void k_pre(const void* __restrict__ vb, int* __restrict__ flag,
                      const int* __restrict__ batch, int* __restrict__ goff,
                      float* __restrict__ zbase, int zwords,
                      const void* b1, const void* b2, const void* g1,
                      const void* be1, const void* g2, const void* be2,
                      const void* __restrict__ w1, const void* __restrict__ w2,
                      float* __restrict__ pc, u16* __restrict__ Wsw) {
    __shared__ int shm[256];
    int b = blockIdx.x, t = threadIdx.x;
    int zb = (zwords + 255) >> 8;
    if (b == 0) {
        float v = (t < 128) ? bf2f(((const u16*)vb)[t]) : 0.f;
        shm[t] = (t < 128) ? ((fabsf(v) < 1000.f) ? 1 : 0) : 1;
        __syncthreads();
        for (int off = 128; off; off >>= 1) {
            if (t < off) shm[t] &= shm[t + off];
            __syncthreads();
        }
        if (t == 0) *flag = shm[0];
    } else if (b == 1) {
        if (t <= NG) {
            int lo = 0, hi = NN;
            while (lo < hi) {
                int mid = (lo + hi) >> 1;
                if (batch[mid] < t) lo = mid + 1; else hi = mid;
            }
            goff[t] = lo;
        }
    } else if (b < 2 + zb) {
        int i = (b - 2) * 256 + t;
        if (i < zwords) zbase[i] = 0.f;
    } else {
        // local dtype probe (no dependency on block 0)
        float v = (t < 128) ? bf2f(((const u16*)vb)[t]) : 0.f;
        shm[t] = (t < 128) ? ((fabsf(v) < 1000.f) ? 1 : 0) : 1;
        __syncthreads();
        for (int off = 128; off; off >>= 1) {
            if (t < off) shm[t] &= shm[t + off];
            __syncthreads();
        }
        int isbf = shm[0];
        int bb = b - 2 - zb;
        if (bb < 12) {
            int i = bb * 256 + t;            // < 3072 exactly
            int p = i >> 9, j = i & 511;
            const void* s = (p == 0) ? b1 : (p == 1) ? b2 : (p == 2) ? g1
                          : (p == 3) ? be1 : (p == 4) ? g2 : be2;
            pc[i] = ldf(s, j, isbf);
        } else {
            int i = (bb - 12) * 256 + t;     // < 131072 exactly
            int m    = i >> 14;
            int idx  = i & 16383;
            int nt   = idx >> 11;
            int ks   = (idx >> 9) & 3;
            int lane = (idx >> 3) & 63;
            int j    = idx & 7;
            int row = ks * 32 + (lane >> 4) * 8 + j;
            int col = nt * 16 + (lane & 15);
            const void* src = (m < 4) ? w1 : w2;
            size_t off = (size_t)(m & 3) * DD * DD + (size_t)row * DD + col;
            Wsw[i] = f2bf(ldf(src, off, isbf));
        }
    }
}

__global__ void k_deg(const int* __restrict__ dst, int* __restrict__ deg) {
    int i = blockIdx.x * 256 + threadIdx.x;
    if (i < NE) atomicAdd(&deg[dst[i]], 1);
}

// scan stage 1 + (last-block) stage 2: per-block sums -> exclusive scan of bsum.
// Device-scope atomics for cross-XCD visibility within the kernel.
__global__ void k_scan12(const int* __restrict__ deg, int* __restrict__ bsum,
                         int* __restrict__ sem) {
    __shared__ int S[256];
    __shared__ int lastB;
    int b = blockIdx.x, t = threadIdx.x;
    int i = b * 256 + t;
    S[t] = (i < NN) ? deg[i] : 0;
    __syncthreads();
    for (int off = 128; off; off >>= 1) {
        if (t < off) S[t] += S[t + off];
        __syncthreads();
    }
    if (t == 0) {
        atomicExch(&bsum[b], S[0]);
        __threadfence();
        lastB = (atomicAdd(&sem[0], 1) == gridDim.x - 1);
    }
    __syncthreads();
    if (!lastB) return;
    __threadfence();
    int v = (t < NB) ? atomicAdd(&bsum[t], 0) : 0;
    S[t] = v;
    __syncthreads();
    for (int off = 1; off < 256; off <<= 1) {
        int x = (t >= off) ? S[t - off] : 0;
        __syncthreads();
        S[t] += x;
        __syncthreads();
    }
    if (t < NB) bsum[t] = S[t] - v;                 // exclusive
}

// merged: blocks 0..NB-1 finish the rowptr scan; blocks NB.. compute
// h0 = vw[feat] + vb + deg_emb[min(deg,1000)] -> B (bf16).
// Init phase vectorized: 8 cols/thread, uint4 loads/stores.
__global__ void k_scan3init(const int* __restrict__ deg, const int* __restrict__ bsum,
                            int* __restrict__ rowptr,
                            const int* __restrict__ feat, const void* __restrict__ vw,
                            const void* __restrict__ vb, const void* __restrict__ demb,
                            u16* __restrict__ B, const int* __restrict__ flag) {
    __shared__ int S[256];
    int b = blockIdx.x, t = threadIdx.x;
    if (b < NB) {
        int i = b * 256 + t;
        int v = (i < NN) ? deg[i] : 0;
        S[t] = v;
        __syncthreads();
        for (int off = 1; off < 256; off <<= 1) {
            int x = (t >= off) ? S[t - off] : 0;
            __syncthreads();
            S[t] += x;
            __syncthreads();
        }
        if (i < NN) rowptr[i] = bsum[b] + S[t] - v;
        if (i == NN - 1) rowptr[NN] = bsum[b] + S[t];   // == NE
    } else {
        int idx = (b - NB) * 256 + t;            // < 800000 exactly
        if (idx >= NN * DD / 8) return;
        int n  = idx >> 4;                       // 16 threads per node
        int c8 = (idx & 15) * 8;
        int isbf = *flag;
        int f  = feat[n] % FIXED_DIM;
        int dg = min(deg[n], 1000);
        float x[8];
        if (isbf) {
            uint4 a4 = *(const uint4*)((const u16*)vw + (size_t)f * DD + c8);
            uint4 b4 = *(const uint4*)((const u16*)vb + c8);
            uint4 d4 = *(const uint4*)((const u16*)demb + (size_t)dg * DD + c8);
            u32 aw[4] = {a4.x, a4.y, a4.z, a4.w};
            u32 bw[4] = {b4.x, b4.y, b4.z, b4.w};
            u32 dw[4] = {d4.x, d4.y, d4.z, d4.w};
            #pragma unroll
            for (int e = 0; e < 8; e++) {
                int wi = e >> 1, sh = (e & 1) * 16;
                x[e] = bf2f((u16)(aw[wi] >> sh)) + bf2f((u16)(bw[wi] >> sh))
                     + bf2f((u16)(dw[wi] >> sh));
            }
        } else {
            const float* vwp = (const float*)vw + (size_t)f * DD + c8;
            const float* vbp = (const float*)vb + c8;
            const float* dep = (const float*)demb + (size_t)dg * DD + c8;
            #pragma unroll
            for (int e = 0; e < 8; e++) x[e] = vwp[e] + vbp[e] + dep[e];
        }
        u32 o0 = ((u32)f2bf(x[1]) << 16) | (u32)f2bf(x[0]);
        u32 o1 = ((u32)f2bf(x[3]) << 16) | (u32)f2bf(x[2]);
        u32 o2 = ((u32)f2bf(x[5]) << 16) | (u32)f2bf(x[4]);
        u32 o3 = ((u32)f2bf(x[7]) << 16) | (u32)f2bf(x[6]);
        *(uint4*)&B[(size_t)idx * 8] = make_uint4(o0, o1, o2, o3);
    }
}

__global__ void k_fill(const int* __restrict__ src, const int* __restrict__ dst,
                       const int* __restrict__ rowptr, int* __restrict__ cursor,
                       int* __restrict__ colidx) {
    int e = blockIdx.x * 256 + threadIdx.x;
    if (e >= NE) return;
    int d = dst[e];
    int p = atomicAdd(&cursor[d], 1);
    colidx[rowptr[d] + p] = src[e];
}

// GIN aggregation with fused h-recompute, bf16 out (proven structure:
// 1 row/wave, 2 cols/lane, occupancy 8 -> max TLP for the latency-bound gather).
//   f(x) = AFF ? relu(a[c]*x + b[c]) : x   (a,b from prev layer's BN2 stats)
//   Agg[n] = f(B[n]) + sum_{j in row n} f(B[colidx[j]])
template <bool AFF>
__global__ __launch_bounds__(256, 8) void k_aggr(
        const u16* __restrict__ B, const int* __restrict__ rowptr,
        const int* __restrict__ colidx,
        const float* __restrict__ gIn, const float* __restrict__ bIn,
        const float* __restrict__ sIn, const float* __restrict__ qIn,
        u16* __restrict__ Agg) {
    int n = blockIdx.x * 4 + (threadIdx.x >> 6);
    if (n >= NN) return;
    int c = (threadIdx.x & 63) * 2;
    float a0 = 1.f, b0 = 0.f, a1 = 1.f, b1 = 0.f;
    if (AFF) {
        float inv = 1.0f / (float)NN;
        float mu0 = sIn[c] * inv, mu1 = sIn[c + 1] * inv;
        float v0 = fmaxf(qIn[c] * inv - mu0 * mu0, 0.f);
        float v1 = fmaxf(qIn[c + 1] * inv - mu1 * mu1, 0.f);
        a0 = gIn[c] * rsqrtf(v0 + BN_EPS);
        a1 = gIn[c + 1] * rsqrtf(v1 + BN_EPS);
        b0 = bIn[c] - a0 * mu0;
        b1 = bIn[c + 1] - a1 * mu1;
    }
    u32 w = *(const u32*)&B[(size_t)n * DD + c];
    float x0 = bf2f((u16)(w & 0xFFFF)), x1 = bf2f((u16)(w >> 16));
    float s0 = AFF ? fmaxf(fmaf(a0, x0, b0), 0.f) : x0;
    float s1 = AFF ? fmaxf(fmaf(a1, x1, b1), 0.f) : x1;
    int lo = rowptr[n], hi = rowptr[n + 1];
    int j = lo;
    for (; j + 4 <= hi; j += 4) {
        int m0 = colidx[j], m1 = colidx[j + 1];
        int m2 = colidx[j + 2], m3 = colidx[j + 3];
        u32 w0 = *(const u32*)&B[(size_t)m0 * DD + c];
        u32 w1v = *(const u32*)&B[(size_t)m1 * DD + c];
        u32 w2v = *(const u32*)&B[(size_t)m2 * DD + c];
        u32 w3v = *(const u32*)&B[(size_t)m3 * DD + c];
        float y;
        y = bf2f((u16)(w0 & 0xFFFF)); s0 += AFF ? fmaxf(fmaf(a0, y, b0), 0.f) : y;
        y = bf2f((u16)(w0 >> 16));    s1 += AFF ? fmaxf(fmaf(a1, y, b1), 0.f) : y;
        y = bf2f((u16)(w1v & 0xFFFF)); s0 += AFF ? fmaxf(fmaf(a0, y, b0), 0.f) : y;
        y = bf2f((u16)(w1v >> 16));    s1 += AFF ? fmaxf(fmaf(a1, y, b1), 0.f) : y;
        y = bf2f((u16)(w2v & 0xFFFF)); s0 += AFF ? fmaxf(fmaf(a0, y, b0), 0.f) : y;
        y = bf2f((u16)(w2v >> 16));    s1 += AFF ? fmaxf(fmaf(a1, y, b1), 0.f) : y;
        y = bf2f((u16)(w3v & 0xFFFF)); s0 += AFF ? fmaxf(fmaf(a0, y, b0), 0.f) : y;
        y = bf2f((u16)(w3v >> 16));    s1 += AFF ? fmaxf(fmaf(a1, y, b1), 0.f) : y;
    }
    for (; j < hi; j++) {
        int m = colidx[j];
        w = *(const u32*)&B[(size_t)m * DD + c];
        x0 = bf2f((u16)(w & 0xFFFF)); x1 = bf2f((u16)(w >> 16));
        s0 += AFF ? fmaxf(fmaf(a0, x0, b0), 0.f) : x0;
        s1 += AFF ? fmaxf(fmaf(a1, x1, b1), 0.f) : x1;
    }
    *(u32*)&Agg[(size_t)n * DD + c] = ((u32)f2bf(s1) << 16) | (u32)f2bf(s0);
}

// ---- MFMA GEMM, 128x128 per block: LDS W-staging + direct-global A ----
// ROUND-9 PROVEN FORM (reverted from round-10/11 direct-global W, which
// regressed +3us/dispatch: the streaming A operand thrashes the 32KB L1,
// so "L1-resident W" never holds — LDS is the correct home for the
// block-reused operand). Direct-global A (round-7 win) retained.
// LDS: Wl 32K + Red 4K + affS 1K = 37KB -> 3 blocks/CU.
template <bool IN16, bool OUT16, bool AFF>
__global__ __launch_bounds__(256, 3) void k_gemm(
        const void* In, const u16* __restrict__ Wsw,
        const float* __restrict__ bias,
        const float* __restrict__ gIn, const float* __restrict__ bIn,
        const float* __restrict__ sIn, const float* __restrict__ qIn,
        void* Out, float* __restrict__ ssum, float* __restrict__ ssq,
        int nRows) {
    __shared__ u16 Wl[16384];          // 32 KB swizzled W
    __shared__ float RedS[512];
    __shared__ float RedQ[512];
    __shared__ float affS[256];
    const int t = threadIdx.x;
    const int row0 = blockIdx.x * 128;

    // stage swizzled W: 2048 uint4
    {
        const uint4* s = (const uint4*)Wsw;
        uint4* d = (uint4*)Wl;
        #pragma unroll
        for (int i = 0; i < 8; i++) d[t + i * 256] = s[t + i * 256];
    }
    if (AFF && t < 128) {
        float inv = 1.0f / (float)NN;
        float mu = sIn[t] * inv;
        float var = fmaxf(qIn[t] * inv - mu * mu, 0.f);
        float a = gIn[t] * rsqrtf(var + BN_EPS);
        affS[t] = a;
        affS[128 + t] = bIn[t] - a * mu;
    }
    __syncthreads();

    const int w    = t >> 6;
    const int ln   = t & 63;
    const int quad = ln >> 4;
    const int lq   = ln & 15;
    const int r0g  = row0 + w * 32 + lq;     // M-tile 0 row
    const int r1g  = r0g + 16;               // M-tile 1 row

    // A fragments directly from global (zeros for OOB rows, as staged did)
    bf16x8 af0[4], af1[4];
    #pragma unroll
    for (int ks = 0; ks < 4; ks++) {
        const int cb = quad * 8 + ks * 32;
        if (IN16) {
            const u16* p = (const u16*)In;
            af0[ks] = (r0g < nRows) ? *(const bf16x8*)&p[(size_t)r0g * DD + cb]
                                    : (bf16x8){0,0,0,0,0,0,0,0};
            af1[ks] = (r1g < nRows) ? *(const bf16x8*)&p[(size_t)r1g * DD + cb]
                                    : (bf16x8){0,0,0,0,0,0,0,0};
        } else {
            const float* p = (const float*)In;
            bf16x8 v0 = {0,0,0,0,0,0,0,0}, v1 = {0,0,0,0,0,0,0,0};
            if (r0g < nRows) {
                const float* rp = p + (size_t)r0g * DD + cb;
                float4 lo = *(const float4*)rp;
                float4 hi = *(const float4*)(rp + 4);
                float xs[8] = {lo.x, lo.y, lo.z, lo.w, hi.x, hi.y, hi.z, hi.w};
                #pragma unroll
                for (int e = 0; e < 8; e++) {
                    float x = xs[e];
                    if (AFF) x = fmaxf(fmaf(affS[cb + e], x, affS[128 + cb + e]), 0.f);
                    v0[e] = (short)f2bf(x);
                }
            }
            if (r1g < nRows) {
                const float* rp = p + (size_t)r1g * DD + cb;
                float4 lo = *(const float4*)rp;
                float4 hi = *(const float4*)(rp + 4);
                float xs[8] = {lo.x, lo.y, lo.z, lo.w, hi.x, hi.y, hi.z, hi.w};
                #pragma unroll
                for (int e = 0; e < 8; e++) {
                    float x = xs[e];
                    if (AFF) x = fmaxf(fmaf(affS[cb + e], x, affS[128 + cb + e]), 0.f);
                    v1[e] = (short)f2bf(x);
                }
            }
            af0[ks] = v0;
            af1[ks] = v1;
        }
    }

    f32x4 acc0[8], acc1[8];
    #pragma unroll
    for (int nt = 0; nt < 8; nt++) {
        acc0[nt] = (f32x4){0.f, 0.f, 0.f, 0.f};
        acc1[nt] = (f32x4){0.f, 0.f, 0.f, 0.f};
    }
    #pragma unroll
    for (int ks = 0; ks < 4; ks++) {
        #pragma unroll
        for (int nt = 0; nt < 8; nt++) {
            bf16x8 b = *(const bf16x8*)&Wl[((nt * 4 + ks) * 64 + ln) * 8];
            acc0[nt] = __builtin_amdgcn_mfma_f32_16x16x32_bf16(af0[ks], b, acc0[nt], 0, 0, 0);
            acc1[nt] = __builtin_amdgcn_mfma_f32_16x16x32_bf16(af1[ks], b, acc1[nt], 0, 0, 0);
        }
    }

    // epilogue: D[row=quad*4+r][col=nt*16+lq] for both M-tiles
    const int rb0 = row0 + w * 32 + quad * 4;
    const int rb1 = rb0 + 16;
    #pragma unroll
    for (int nt = 0; nt < 8; nt++) {
        int col = nt * 16 + lq;
        float bv = bias[col];
        float s = 0.f, q = 0.f;
        #pragma unroll
        for (int r = 0; r < 4; r++) {
            int gr = rb0 + r;
            if (gr < nRows) {
                float val = acc0[nt][r] + bv;
                size_t o = (size_t)gr * DD + col;
                if (OUT16) ((u16*)Out)[o] = f2bf(val);
                else       ((float*)Out)[o] = val;
                s += val; q += val * val;
            }
        }
        #pragma unroll
        for (int r = 0; r < 4; r++) {
            int gr = rb1 + r;
            if (gr < nRows) {
                float val = acc1[nt][r] + bv;
                size_t o = (size_t)gr * DD + col;
                if (OUT16) ((u16*)Out)[o] = f2bf(val);
                else       ((float*)Out)[o] = val;
                s += val; q += val * val;
            }
        }
        s += __shfl_xor(s, 16); q += __shfl_xor(q, 16);
        s += __shfl_xor(s, 32); q += __shfl_xor(q, 32);
        if (quad == 0) { RedS[w * 128 + col] = s; RedQ[w * 128 + col] = q; }
    }
    __syncthreads();
    if (t < 128) {
        float s = RedS[t] + RedS[128 + t] + RedS[256 + t] + RedS[384 + t];
        float q = RedQ[t] + RedQ[128 + t] + RedQ[256 + t] + RedQ[384 + t];
        atomicAdd(&ssum[t], s);
        atomicAdd(&ssq[t], q);
    }
}

// final h = relu(a*z2+b) -> A (fp32) + pool partials; last block divides.
// (round-7 form, best measured; d_out write path caps this kernel ~45us)
__global__ __launch_bounds__(256, 4) void k_upool(
        const u16* __restrict__ Bz,
        const float* __restrict__ gIn, const float* __restrict__ bIn,
        const float* __restrict__ sIn, const float* __restrict__ qIn,
        const int* __restrict__ batch, float* __restrict__ A,
        float* __restrict__ gsum, const int* __restrict__ goff,
        float* __restrict__ outw, int* __restrict__ sem) {
    const int t = threadIdx.x;
    const int c = (t & 63) * 2;        // 2 cols per lane
    const int qv = t >> 6;             // rows qv + 4i (wave-uniform row)
    const int r0 = blockIdx.x * 64;
    const int g_lo = batch[r0];
    const int g_hi = batch[min(r0 + 63, NN - 1)];
    float inv = 1.0f / (float)NN;
    float mu0 = sIn[c] * inv, mu1 = sIn[c + 1] * inv;
    float v0 = fmaxf(qIn[c] * inv - mu0 * mu0, 0.f);
    float v1 = fmaxf(qIn[c + 1] * inv - mu1 * mu1, 0.f);
    float a0 = gIn[c] * rsqrtf(v0 + BN_EPS);
    float a1 = gIn[c + 1] * rsqrtf(v1 + BN_EPS);
    float b0 = bIn[c] - a0 * mu0;
    float b1 = bIn[c + 1] - a1 * mu1;
    float lo0 = 0.f, lo1 = 0.f, hi0 = 0.f, hi1 = 0.f;
    #pragma unroll
    for (int i = 0; i < 16; i++) {
        int r = r0 + qv + 4 * i;
        if (r >= NN) break;
        u32 wd = *(const u32*)&Bz[(size_t)r * DD + c];
        float x0 = fmaxf(fmaf(a0, bf2f((u16)(wd & 0xFFFF)), b0), 0.f);
        float x1 = fmaxf(fmaf(a1, bf2f((u16)(wd >> 16)), b1), 0.f);
        *(float2*)&A[(size_t)r * DD + c] = make_float2(x0, x1);
        if (batch[r] == g_lo) { lo0 += x0; lo1 += x1; }
        else                  { hi0 += x0; hi1 += x1; }
    }
    __shared__ float2 PL[4][64];
    __shared__ float2 PH[4][64];
    PL[qv][t & 63] = make_float2(lo0, lo1);
    PH[qv][t & 63] = make_float2(hi0, hi1);
    __syncthreads();
    if (t < 64) {
        float2 p0 = PL[0][t], p1 = PL[1][t], p2 = PL[2][t], p3 = PL[3][t];
        atomicAdd(&gsum[(size_t)g_lo * DD + 2 * t],     p0.x + p1.x + p2.x + p3.x);
        atomicAdd(&gsum[(size_t)g_lo * DD + 2 * t + 1], p0.y + p1.y + p2.y + p3.y);
    } else if (t < 128 && g_hi != g_lo) {
        int u = t - 64;
        float2 p0 = PH[0][u], p1 = PH[1][u], p2 = PH[2][u], p3 = PH[3][u];
        atomicAdd(&gsum[(size_t)g_hi * DD + 2 * u],     p0.x + p1.x + p2.x + p3.x);
        atomicAdd(&gsum[(size_t)g_hi * DD + 2 * u + 1], p0.y + p1.y + p2.y + p3.y);
    }

    __shared__ int lastF;
    if (t == 0) {
        __threadfence();
        lastF = (atomicAdd(&sem[1], 1) == gridDim.x - 1);
    }
    __syncthreads();
    if (!lastF) return;
    __threadfence();
    for (int i = t; i < NG * DD; i += 256) {
        int g = i >> 7;
        float cnt = fmaxf((float)(goff[g + 1] - goff[g]), 1.0f);
        outw[i] = atomicAdd(&gsum[i], 0.0f) / cnt;
    }
}

extern "C" void kernel_launch(void* const* d_in, const int* in_sizes, int n_in,
                              void* d_out, int out_size, void* d_ws, size_t ws_size,
                              hipStream_t stream) {
    const int* feat  = (const int*)d_in[0];
    const int* ei    = (const int*)d_in[1];
    const int* batch = (const int*)d_in[2];
    const void* vw   = d_in[3];
    const void* vb   = d_in[4];
    const void* demb = d_in[5];
    const void* w1   = d_in[6];
    const void* b1   = d_in[7];
    const void* g1   = d_in[8];
    const void* be1  = d_in[9];
    const void* w2   = d_in[10];
    const void* b2   = d_in[11];
    const void* g2   = d_in[12];
    const void* be2  = d_in[13];

    const int* src = ei;
    const int* dst = ei + NE;
    const size_t ND = (size_t)NN * DD;

    // ---- workspace layout ----
    float* pc     = (float*)d_ws;            // 3072: b1,b2,g1,be1,g2,be2
    int*   flag   = (int*)(pc + 3072);       // 64
    float* stats  = (float*)(flag + 64);     // 2048 [zero from here...]
    float* gsum   = stats + 2048;            // 8192
    int*   deg    = (int*)(gsum + 8192);     // NN
    int*   cursor = deg + NN;                // NN
    int*   sem    = cursor + NN;             // 64  [...to here]
    int*   bsum   = sem + 64;                // 256
    int*   goff   = bsum + 256;              // 128 (65 used)
    int*   rowptr = goff + 128;              // NN+64
    int*   colidx = rowptr + NN + 64;        // NE
    u16*   Wsw    = (u16*)(colidx + NE);     // 8*16384 u16
    u16*   B      = Wsw + 8 * 16384;         // ND bf16
    u16*   Agg16  = B + ND;                  // ND bf16
    float* Z      = (float*)(Agg16 + ND);    // ND fp32: z1 scratch (in ws)

    float* b1c  = pc;
    float* b2c  = pc + 512;
    float* g1c  = pc + 1024;
    float* be1c = pc + 1536;
    float* g2c  = pc + 2048;
    float* be2c = pc + 2560;
    float* sum1 = stats;          // [NL][128]
    float* sq1  = stats + 512;
    float* sum2 = stats + 1024;
    float* sq2  = stats + 1536;

    float* outw = (float*)d_out;             // [0, NG*DD): graph_feature
    float* A    = outw + (size_t)NG * DD;    // final h (fp32) — d_out only

    const int zwords = 2048 + 8192 + NN + NN + 64;  // stats, gsum, deg, cursor, sem
    const int zb = (zwords + 255) / 256;            // 431
    const int initBlocks = (int)(ND / 8 / 256);     // 3125 exact
    const int gemmBlocks = (NN + 127) / 128;        // 391
    const int aggrBlocks = (NN + 3) / 4;            // 12500

    k_pre<<<2 + zb + 12 + 512, 256, 0, stream>>>(vb, flag, batch, goff,
                                                 stats, zwords,
                                                 b1, b2, g1, be1, g2, be2,
                                                 w1, w2, pc, Wsw);
    k_deg<<<(NE + 255) / 256, 256, 0, stream>>>(dst, deg);
    k_scan12<<<NB, 256, 0, stream>>>(deg, bsum, sem);
    k_scan3init<<<NB + initBlocks, 256, 0, stream>>>(deg, bsum, rowptr,
                                                     feat, vw, vb, demb, B, flag);
    k_fill<<<(NE + 255) / 256, 256, 0, stream>>>(src, dst, rowptr, cursor, colidx);

    for (int l = 0; l < NL; l++) {
        const u16* W1l = Wsw + (size_t)l * 16384;
        const u16* W2l = Wsw + (size_t)(4 + l) * 16384;
        if (l == 0) {
            k_aggr<false><<<aggrBlocks, 256, 0, stream>>>(
                B, rowptr, colidx, nullptr, nullptr, nullptr, nullptr, Agg16);
        } else {
            k_aggr<true><<<aggrBlocks, 256, 0, stream>>>(
                B, rowptr, colidx, g2c + (l - 1) * 128, be2c + (l - 1) * 128,
                sum2 + (l - 1) * 128, sq2 + (l - 1) * 128, Agg16);
        }
        // GEMM1: Agg16 (bf16) -> Z (fp32 z1, in workspace)
        k_gemm<true, false, false><<<gemmBlocks, 256, 0, stream>>>(
            Agg16, W1l, b1c + l * 128, nullptr, nullptr, nullptr, nullptr,
            Z, sum1 + l * 128, sq1 + l * 128, NN);
        // GEMM2: Z (fp32 z1) -> B (bf16 z2), affine from BN1 stats
        k_gemm<false, true, true><<<gemmBlocks, 256, 0, stream>>>(
            Z, W2l, b2c + l * 128, g1c + l * 128, be1c + l * 128,
            sum1 + l * 128, sq1 + l * 128,
            B, sum2 + l * 128, sq2 + l * 128, NN);
    }
    k_upool<<<(NN + 63) / 64, 256, 0, stream>>>(
        B, g2c + 3 * 128, be2c + 3 * 128, sum2 + 3 * 128, sq2 + 3 * 128,
        batch, A, gsum, goff, outw, sem);
}